// Round 1
// baseline (263.046 us; speedup 1.0000x reference)
//
#include <hip/hip_runtime.h>

#define TPB 512

__device__ __forceinline__ unsigned bf16_rne(float f) {
    unsigned u = __float_as_uint(f);
    return (u + 0x7fffu + ((u >> 16) & 1u)) >> 16;
}

// One block per sample. 512 threads:
//   thread t owns h_t (W1 column t in fp32 registers, 128 VGPR)
//   thread t also owns W2[kb..kb+127][j] (j = t&127, kb = 128*(t>>7)) as packed bf16 (64 VGPR)
__global__ __launch_bounds__(TPB, 2) void vi_node_kernel(
    const float* __restrict__ x0, const float* __restrict__ W1,
    const float* __restrict__ b1, const float* __restrict__ u1,
    const float* __restrict__ W2, const float* __restrict__ b2,
    const int* __restrict__ nsp, float* __restrict__ out, int nB)
{
    const int s    = blockIdx.x;
    const int t    = threadIdx.x;
    const int j    = t & 127;
    const int q    = t >> 7;
    const int kb   = q << 7;
    const int lane = t & 63;
    const int wid  = t >> 6;

    __shared__ __align__(16) float xs[128];      // stage input
    __shared__ __align__(16) float ys[128];      // base state y_n
    __shared__ __align__(16) float aL[512];      // tanh activations
    __shared__ __align__(16) float part[4][128]; // dxdt partials
    __shared__ __align__(16) float kx[6][128];   // RK stage slopes
    __shared__ float wred[16];                   // wave partial sums
    __shared__ float klpS[6], kklS[6];           // scalar stage slopes (thread 0)

    // ---- load weights into registers ----
    float w1r[128];
#pragma unroll
    for (int i = 0; i < 128; ++i) w1r[i] = W1[i * 512 + t];   // coalesced per i

    unsigned w2r[64];
#pragma unroll
    for (int m = 0; m < 64; ++m) {
        float lo = W2[(kb + 2 * m) * 128 + j];
        float hi = W2[(kb + 2 * m + 1) * 128 + j];
        w2r[m] = bf16_rne(lo) | (bf16_rne(hi) << 16);
    }

    // wdiag_k = sum_j W1[j,k] * W2[k,j]  (exact fp32)
    float wd = 0.f;
#pragma unroll
    for (int i = 0; i < 128; ++i) wd = fmaf(w1r[i], W2[t * 128 + i], wd);

    const float b1k = b1[t];
    const float u1k = u1[t];
    const float b2j = b2[j];

    const int ns = nsp[0];
    const float dt = 1.f / (float)ns;

    // ---- init state + log_px0 sum of squares ----
    if (t < 128) {
        float xv = x0[s * 128 + t];
        ys[t] = xv;
        xs[t] = xv;
        float sq = xv * xv;
#pragma unroll
        for (int off = 32; off; off >>= 1) sq += __shfl_xor(sq, off, 64);
        if (lane == 0) wred[8 + wid] = sq;
    }
    __syncthreads();
    const float sumsq = wred[8] + wred[9];
    float ld_acc = 0.f, kl_acc = 0.f;   // thread-0 accumulators

// One RHS eval: reads xs, writes kx[STAGE], klpS/kklS[STAGE]. 3 internal barriers.
#define EVAL(STAGE, TVAL)                                                      \
    {                                                                          \
        float h0 = 0.f, h1 = 0.f, h2 = 0.f, h3 = 0.f;                          \
        _Pragma("unroll")                                                      \
        for (int i = 0; i < 128; i += 4) {                                     \
            float4 xv = *(const float4*)&xs[i];   /* LDS broadcast */          \
            h0 = fmaf(xv.x, w1r[i],     h0);                                   \
            h1 = fmaf(xv.y, w1r[i + 1], h1);                                   \
            h2 = fmaf(xv.z, w1r[i + 2], h2);                                   \
            h3 = fmaf(xv.w, w1r[i + 3], h3);                                   \
        }                                                                      \
        float hh = fmaf((TVAL), u1k, b1k) + ((h0 + h1) + (h2 + h3));           \
        float ee = __expf(2.f * hh);                                           \
        float aa = 1.f - 2.f / (ee + 1.f);       /* tanh */                    \
        aL[t] = aa;                                                            \
        float trp = (1.f - aa * aa) * wd;                                      \
        _Pragma("unroll")                                                      \
        for (int off = 32; off; off >>= 1) trp += __shfl_xor(trp, off, 64);    \
        if (lane == 0) wred[wid] = trp;                                        \
        __syncthreads();                          /* B1: a + tr partials */    \
        float p0 = 0.f, p1 = 0.f, p2 = 0.f, p3 = 0.f;                          \
        _Pragma("unroll")                                                      \
        for (int mm = 0; mm < 16; ++mm) {                                      \
            float4 av = *(const float4*)&aL[kb + 4 * mm]; /* broadcast */      \
            unsigned wA = w2r[2 * mm], wB = w2r[2 * mm + 1];                   \
            p0 = fmaf(av.x, __uint_as_float(wA << 16),         p0);            \
            p1 = fmaf(av.y, __uint_as_float(wA & 0xffff0000u), p1);            \
            p2 = fmaf(av.z, __uint_as_float(wB << 16),         p2);            \
            p3 = fmaf(av.w, __uint_as_float(wB & 0xffff0000u), p3);            \
        }                                                                      \
        part[q][j] = (p0 + p1) + (p2 + p3);                                    \
        __syncthreads();                          /* B2: partials ready */     \
        if (t < 128) {                                                         \
            float dx = ((part[0][t] + part[1][t]) + (part[2][t] + part[3][t])) \
                       + b2j;                                                  \
            kx[STAGE][t] = dx;                                                 \
            float xd = xs[t] * dx;                                             \
            _Pragma("unroll")                                                  \
            for (int off = 32; off; off >>= 1) xd += __shfl_xor(xd, off, 64);  \
            if (lane == 0) wred[8 + wid] = xd;                                 \
        }                                                                      \
        __syncthreads();                          /* B3: kx + dot partials */  \
        if (t == 0) {                                                          \
            float tr = ((wred[0] + wred[1]) + (wred[2] + wred[3]))             \
                     + ((wred[4] + wred[5]) + (wred[6] + wred[7]));            \
            float dotv = wred[8] + wred[9];                                    \
            klpS[STAGE] = -tr;                                                 \
            kklS[STAGE] = dotv - tr;                                           \
        }                                                                      \
    }

    for (int n = 0; n < ns; ++n) {
        const float tn = (float)n;

        EVAL(0, dt * tn);
        if (t < 128) xs[t] = fmaf(dt, 0.2f * kx[0][t], ys[t]);
        __syncthreads();

        EVAL(1, dt * (tn + 0.2f));
        if (t < 128) xs[t] = fmaf(dt, 0.075f * kx[0][t] + 0.225f * kx[1][t], ys[t]);
        __syncthreads();

        EVAL(2, dt * (tn + 0.3f));
        if (t < 128) xs[t] = fmaf(dt,
              (float)(44.0/45.0)  * kx[0][t] + (float)(-56.0/15.0) * kx[1][t]
            + (float)(32.0/9.0)   * kx[2][t], ys[t]);
        __syncthreads();

        EVAL(3, dt * (tn + 0.8f));
        if (t < 128) xs[t] = fmaf(dt,
              (float)(19372.0/6561.0)  * kx[0][t] + (float)(-25360.0/2187.0) * kx[1][t]
            + (float)(64448.0/6561.0)  * kx[2][t] + (float)(-212.0/729.0)    * kx[3][t], ys[t]);
        __syncthreads();

        EVAL(4, dt * (tn + (float)(8.0/9.0)));
        if (t < 128) xs[t] = fmaf(dt,
              (float)(9017.0/3168.0)   * kx[0][t] + (float)(-355.0/33.0)     * kx[1][t]
            + (float)(46732.0/5247.0)  * kx[2][t] + (float)(49.0/176.0)      * kx[3][t]
            + (float)(-5103.0/18656.0) * kx[4][t], ys[t]);
        __syncthreads();

        EVAL(5, dt * (tn + 1.0f));
        if (t < 128) {
            float sum = (float)(35.0/384.0)    * kx[0][t] + (float)(500.0/1113.0) * kx[2][t]
                      + (float)(125.0/192.0)   * kx[3][t] + (float)(-2187.0/6784.0) * kx[4][t]
                      + (float)(11.0/84.0)     * kx[5][t];
            float yv = fmaf(dt, sum, ys[t]);
            ys[t] = yv;
            xs[t] = yv;
        }
        if (t == 0) {
            ld_acc += dt * ((float)(35.0/384.0)  * klpS[0] + (float)(500.0/1113.0)   * klpS[2]
                          + (float)(125.0/192.0) * klpS[3] + (float)(-2187.0/6784.0) * klpS[4]
                          + (float)(11.0/84.0)   * klpS[5]);
            kl_acc += dt * ((float)(35.0/384.0)  * kklS[0] + (float)(500.0/1113.0)   * kklS[2]
                          + (float)(125.0/192.0) * kklS[3] + (float)(-2187.0/6784.0) * kklS[4]
                          + (float)(11.0/84.0)   * kklS[5]);
        }
        __syncthreads();
    }

    // ---- outputs: z (B,D) | log_px (B) | kl (B) ----
    if (t < 128) out[s * 128 + t] = ys[t];
    if (t == 0) {
        const float LOG2PI = 1.8378770664093454f;
        float lpx0 = -0.5f * sumsq - 0.5f * 128.f * LOG2PI;
        out[nB * 128 + s]      = lpx0 + ld_acc;
        out[nB * 128 + nB + s] = kl_acc;
    }
#undef EVAL
}

extern "C" void kernel_launch(void* const* d_in, const int* in_sizes, int n_in,
                              void* d_out, int out_size, void* d_ws, size_t ws_size,
                              hipStream_t stream) {
    const float* x0 = (const float*)d_in[0];
    const float* W1 = (const float*)d_in[1];
    const float* b1 = (const float*)d_in[2];
    const float* u1 = (const float*)d_in[3];
    const float* W2 = (const float*)d_in[4];
    const float* b2 = (const float*)d_in[5];
    const int*  nsp = (const int*)d_in[6];
    float* out = (float*)d_out;
    const int nB = in_sizes[0] / 128;   // 128 samples

    hipLaunchKernelGGL(vi_node_kernel, dim3(nB), dim3(TPB), 0, stream,
                       x0, W1, b1, u1, W2, b2, nsp, out, nB);
}

// Round 2
// 262.975 us; speedup vs baseline: 1.0003x; 1.0003x over previous
//
#include <hip/hip_runtime.h>

#define TPB 512

__device__ __forceinline__ unsigned bf16_rne(float f) {
    unsigned u = __float_as_uint(f);
    return (u + 0x7fffu + ((u >> 16) & 1u)) >> 16;
}

// One block per sample (128 blocks, each alone on a CU). 512 threads:
//   thread t owns h_t (W1 column t in fp32 registers, 128 VGPR)
//   thread t also owns W2[kb..kb+127][j] (j = t&127, kb = 128*(t>>7)) as packed bf16 (64 VGPR)
// __launch_bounds__(512,1): grid=128 < 256 CUs, so >1 block/CU is unreachable;
// 1 block/CU gives the allocator 256 VGPR/wave so w1r/w2r stay in registers
// (512,2 capped VGPR at 128 -> 33 MB of scratch spill, 22.8 MB WRITE_SIZE/dispatch).
__global__ __launch_bounds__(TPB, 1) void vi_node_kernel(
    const float* __restrict__ x0, const float* __restrict__ W1,
    const float* __restrict__ b1, const float* __restrict__ u1,
    const float* __restrict__ W2, const float* __restrict__ b2,
    const int* __restrict__ nsp, float* __restrict__ out, int nB)
{
    const int s    = blockIdx.x;
    const int t    = threadIdx.x;
    const int j    = t & 127;
    const int q    = t >> 7;
    const int kb   = q << 7;
    const int lane = t & 63;
    const int wid  = t >> 6;

    __shared__ __align__(16) float xs[128];      // stage input
    __shared__ __align__(16) float ys[128];      // base state y_n
    __shared__ __align__(16) float aL[512];      // tanh activations
    __shared__ __align__(16) float part[4][128]; // dxdt partials
    __shared__ __align__(16) float kx[6][128];   // RK stage slopes
    __shared__ float wred[16];                   // wave partial sums
    __shared__ float klpS[6], kklS[6];           // scalar stage slopes (thread 0)

    // ---- load weights into registers ----
    float w1r[128];
#pragma unroll
    for (int i = 0; i < 128; ++i) w1r[i] = W1[i * 512 + t];   // coalesced per i

    unsigned w2r[64];
#pragma unroll
    for (int m = 0; m < 64; ++m) {
        float lo = W2[(kb + 2 * m) * 128 + j];
        float hi = W2[(kb + 2 * m + 1) * 128 + j];
        w2r[m] = bf16_rne(lo) | (bf16_rne(hi) << 16);
    }

    // wdiag_k = sum_j W1[j,k] * W2[k,j]  (exact fp32)
    float wd = 0.f;
#pragma unroll
    for (int i = 0; i < 128; ++i) wd = fmaf(w1r[i], W2[t * 128 + i], wd);

    const float b1k = b1[t];
    const float u1k = u1[t];
    const float b2j = b2[j];

    const int ns = nsp[0];
    const float dt = 1.f / (float)ns;

    // ---- init state + log_px0 sum of squares ----
    if (t < 128) {
        float xv = x0[s * 128 + t];
        ys[t] = xv;
        xs[t] = xv;
        float sq = xv * xv;
#pragma unroll
        for (int off = 32; off; off >>= 1) sq += __shfl_xor(sq, off, 64);
        if (lane == 0) wred[8 + wid] = sq;
    }
    __syncthreads();
    const float sumsq = wred[8] + wred[9];
    float ld_acc = 0.f, kl_acc = 0.f;   // thread-0 accumulators

// One RHS eval: reads xs, writes kx[STAGE], klpS/kklS[STAGE]. 3 internal barriers.
#define EVAL(STAGE, TVAL)                                                      \
    {                                                                          \
        float h0 = 0.f, h1 = 0.f, h2 = 0.f, h3 = 0.f;                          \
        _Pragma("unroll")                                                      \
        for (int i = 0; i < 128; i += 4) {                                     \
            float4 xv = *(const float4*)&xs[i];   /* LDS broadcast */          \
            h0 = fmaf(xv.x, w1r[i],     h0);                                   \
            h1 = fmaf(xv.y, w1r[i + 1], h1);                                   \
            h2 = fmaf(xv.z, w1r[i + 2], h2);                                   \
            h3 = fmaf(xv.w, w1r[i + 3], h3);                                   \
        }                                                                      \
        float hh = fmaf((TVAL), u1k, b1k) + ((h0 + h1) + (h2 + h3));           \
        float ee = __expf(2.f * hh);                                           \
        float aa = 1.f - 2.f / (ee + 1.f);       /* tanh */                    \
        aL[t] = aa;                                                            \
        float trp = (1.f - aa * aa) * wd;                                      \
        _Pragma("unroll")                                                      \
        for (int off = 32; off; off >>= 1) trp += __shfl_xor(trp, off, 64);    \
        if (lane == 0) wred[wid] = trp;                                        \
        __syncthreads();                          /* B1: a + tr partials */    \
        float p0 = 0.f, p1 = 0.f, p2 = 0.f, p3 = 0.f;                          \
        _Pragma("unroll")                                                      \
        for (int mm = 0; mm < 16; ++mm) {                                      \
            float4 av = *(const float4*)&aL[kb + 4 * mm]; /* broadcast */      \
            unsigned wA = w2r[2 * mm], wB = w2r[2 * mm + 1];                   \
            p0 = fmaf(av.x, __uint_as_float(wA << 16),         p0);            \
            p1 = fmaf(av.y, __uint_as_float(wA & 0xffff0000u), p1);            \
            p2 = fmaf(av.z, __uint_as_float(wB << 16),         p2);            \
            p3 = fmaf(av.w, __uint_as_float(wB & 0xffff0000u), p3);            \
        }                                                                      \
        part[q][j] = (p0 + p1) + (p2 + p3);                                    \
        __syncthreads();                          /* B2: partials ready */     \
        if (t < 128) {                                                         \
            float dx = ((part[0][t] + part[1][t]) + (part[2][t] + part[3][t])) \
                       + b2j;                                                  \
            kx[STAGE][t] = dx;                                                 \
            float xd = xs[t] * dx;                                             \
            _Pragma("unroll")                                                  \
            for (int off = 32; off; off >>= 1) xd += __shfl_xor(xd, off, 64);  \
            if (lane == 0) wred[8 + wid] = xd;                                 \
        }                                                                      \
        __syncthreads();                          /* B3: kx + dot partials */  \
        if (t == 0) {                                                          \
            float tr = ((wred[0] + wred[1]) + (wred[2] + wred[3]))             \
                     + ((wred[4] + wred[5]) + (wred[6] + wred[7]));            \
            float dotv = wred[8] + wred[9];                                    \
            klpS[STAGE] = -tr;                                                 \
            kklS[STAGE] = dotv - tr;                                           \
        }                                                                      \
    }

    for (int n = 0; n < ns; ++n) {
        const float tn = (float)n;

        EVAL(0, dt * tn);
        if (t < 128) xs[t] = fmaf(dt, 0.2f * kx[0][t], ys[t]);
        __syncthreads();

        EVAL(1, dt * (tn + 0.2f));
        if (t < 128) xs[t] = fmaf(dt, 0.075f * kx[0][t] + 0.225f * kx[1][t], ys[t]);
        __syncthreads();

        EVAL(2, dt * (tn + 0.3f));
        if (t < 128) xs[t] = fmaf(dt,
              (float)(44.0/45.0)  * kx[0][t] + (float)(-56.0/15.0) * kx[1][t]
            + (float)(32.0/9.0)   * kx[2][t], ys[t]);
        __syncthreads();

        EVAL(3, dt * (tn + 0.8f));
        if (t < 128) xs[t] = fmaf(dt,
              (float)(19372.0/6561.0)  * kx[0][t] + (float)(-25360.0/2187.0) * kx[1][t]
            + (float)(64448.0/6561.0)  * kx[2][t] + (float)(-212.0/729.0)    * kx[3][t], ys[t]);
        __syncthreads();

        EVAL(4, dt * (tn + (float)(8.0/9.0)));
        if (t < 128) xs[t] = fmaf(dt,
              (float)(9017.0/3168.0)   * kx[0][t] + (float)(-355.0/33.0)     * kx[1][t]
            + (float)(46732.0/5247.0)  * kx[2][t] + (float)(49.0/176.0)      * kx[3][t]
            + (float)(-5103.0/18656.0) * kx[4][t], ys[t]);
        __syncthreads();

        EVAL(5, dt * (tn + 1.0f));
        if (t < 128) {
            float sum = (float)(35.0/384.0)    * kx[0][t] + (float)(500.0/1113.0) * kx[2][t]
                      + (float)(125.0/192.0)   * kx[3][t] + (float)(-2187.0/6784.0) * kx[4][t]
                      + (float)(11.0/84.0)     * kx[5][t];
            float yv = fmaf(dt, sum, ys[t]);
            ys[t] = yv;
            xs[t] = yv;
        }
        if (t == 0) {
            ld_acc += dt * ((float)(35.0/384.0)  * klpS[0] + (float)(500.0/1113.0)   * klpS[2]
                          + (float)(125.0/192.0) * klpS[3] + (float)(-2187.0/6784.0) * klpS[4]
                          + (float)(11.0/84.0)   * klpS[5]);
            kl_acc += dt * ((float)(35.0/384.0)  * kklS[0] + (float)(500.0/1113.0)   * kklS[2]
                          + (float)(125.0/192.0) * kklS[3] + (float)(-2187.0/6784.0) * kklS[4]
                          + (float)(11.0/84.0)   * kklS[5]);
        }
        __syncthreads();
    }

    // ---- outputs: z (B,D) | log_px (B) | kl (B) ----
    if (t < 128) out[s * 128 + t] = ys[t];
    if (t == 0) {
        const float LOG2PI = 1.8378770664093454f;
        float lpx0 = -0.5f * sumsq - 0.5f * 128.f * LOG2PI;
        out[nB * 128 + s]      = lpx0 + ld_acc;
        out[nB * 128 + nB + s] = kl_acc;
    }
#undef EVAL
}

extern "C" void kernel_launch(void* const* d_in, const int* in_sizes, int n_in,
                              void* d_out, int out_size, void* d_ws, size_t ws_size,
                              hipStream_t stream) {
    const float* x0 = (const float*)d_in[0];
    const float* W1 = (const float*)d_in[1];
    const float* b1 = (const float*)d_in[2];
    const float* u1 = (const float*)d_in[3];
    const float* W2 = (const float*)d_in[4];
    const float* b2 = (const float*)d_in[5];
    const int*  nsp = (const int*)d_in[6];
    float* out = (float*)d_out;
    const int nB = in_sizes[0] / 128;   // 128 samples

    hipLaunchKernelGGL(vi_node_kernel, dim3(nB), dim3(TPB), 0, stream,
                       x0, W1, b1, u1, W2, b2, nsp, out, nB);
}